// Round 1
// baseline (5003.976 us; speedup 1.0000x reference)
//
#include <hip/hip_runtime.h>
#include <hip/hip_bf16.h>
#include <math.h>

#define Hd 64
#define Fd 512
#define Cd 40

__device__ __forceinline__ float bcast(float v, int lane) {
  return __int_as_float(__builtin_amdgcn_readlane(__float_as_int(v), lane));
}

// ---------- preprocessing ----------

__global__ void count_kernel(const int* __restrict__ ei, int E,
                             int* __restrict__ outdeg, int* __restrict__ indeg) {
  int e = blockIdx.x * blockDim.x + threadIdx.x;
  if (e < E) {
    atomicAdd(&outdeg[ei[e]], 1);      // deg over src (matches reference)
    atomicAdd(&indeg[ei[E + e]], 1);   // CSR by dst
  }
}

__global__ void dinv_kernel(const int* __restrict__ outdeg, float* __restrict__ dinv, int n) {
  int i = blockIdx.x * blockDim.x + threadIdx.x;
  if (i < n) dinv[i] = rsqrtf((float)(outdeg[i] + 1));  // +1 self loop; always > 0
}

__global__ __launch_bounds__(1024) void scan_kernel(const int* __restrict__ counts,
                                                    int* __restrict__ row_ptr,
                                                    int* __restrict__ cursor, int n) {
  __shared__ int lds[1024];
  int tid = threadIdx.x;
  int chunk = (n + 1023) >> 10;
  int s = tid * chunk;
  int e = s + chunk; if (e > n) e = n; if (s > n) s = n;
  int sum = 0;
  for (int i = s; i < e; ++i) sum += counts[i];
  lds[tid] = sum;
  __syncthreads();
  for (int off = 1; off < 1024; off <<= 1) {
    int v = (tid >= off) ? lds[tid - off] : 0;
    __syncthreads();
    lds[tid] += v;
    __syncthreads();
  }
  int run = (tid > 0) ? lds[tid - 1] : 0;
  for (int i = s; i < e; ++i) {
    row_ptr[i] = run; cursor[i] = run;
    run += counts[i];
  }
  if (tid == 0) row_ptr[n] = lds[1023];
}

__global__ void scatter_kernel(const int* __restrict__ ei, int E,
                               const float* __restrict__ dinv,
                               int* __restrict__ cursor, int2* __restrict__ epack) {
  int e = blockIdx.x * blockDim.x + threadIdx.x;
  if (e < E) {
    int s = ei[e], d = ei[E + e];
    int pos = atomicAdd(&cursor[d], 1);
    epack[pos] = make_int2(s, __float_as_int(dinv[s] * dinv[d]));
  }
}

// ---------- input projection: h0 = relu(x @ w0 + b0) ----------
// block = 128 threads, 64 nodes/block, reg tile 4 nodes x 8 outs.

#define GIN_BN 64
#define GIN_TK 64

__global__ __launch_bounds__(128) void gin_kernel(const float* __restrict__ x,
                                                  const float* __restrict__ w0,
                                                  const float* __restrict__ b0,
                                                  float* __restrict__ h0, int n) {
  __shared__ float xs[GIN_BN][GIN_TK + 4];
  __shared__ float ws[GIN_TK][Hd];
  int tid = threadIdx.x;
  int o_grp = tid & 7;    // 8 groups x 8 outs
  int n_grp = tid >> 3;   // 16 groups x 4 nodes
  int o0 = o_grp * 8;
  int base = blockIdx.x * GIN_BN;
  float acc[4][8];
  #pragma unroll
  for (int i = 0; i < 4; ++i)
    #pragma unroll
    for (int j = 0; j < 8; ++j) acc[i][j] = 0.f;

  for (int k0 = 0; k0 < Fd; k0 += GIN_TK) {
    int r  = tid >> 1;
    int c0 = (tid & 1) * 32;
    int gr = base + r;
    const float* src  = x + (size_t)gr * Fd + k0 + c0;
    const float* wsrc = w0 + (size_t)(k0 + r) * Hd + c0;
    #pragma unroll
    for (int q = 0; q < 8; ++q) {
      float4 v = (gr < n) ? *(const float4*)(src + q * 4) : make_float4(0.f, 0.f, 0.f, 0.f);
      *(float4*)&xs[r][c0 + q * 4] = v;
      *(float4*)&ws[r][c0 + q * 4] = *(const float4*)(wsrc + q * 4);
    }
    __syncthreads();
    #pragma unroll 4
    for (int k = 0; k < GIN_TK; ++k) {
      float xv[4];
      #pragma unroll
      for (int i = 0; i < 4; ++i) xv[i] = xs[n_grp * 4 + i][k];
      float wv[8];
      *(float4*)&wv[0] = *(float4*)&ws[k][o0];
      *(float4*)&wv[4] = *(float4*)&ws[k][o0 + 4];
      #pragma unroll
      for (int i = 0; i < 4; ++i)
        #pragma unroll
        for (int j = 0; j < 8; ++j) acc[i][j] += xv[i] * wv[j];
    }
    __syncthreads();
  }
  #pragma unroll
  for (int i = 0; i < 4; ++i) {
    int gr = base + n_grp * 4 + i;
    if (gr < n) {
      #pragma unroll
      for (int j = 0; j < 8; ++j) {
        float v = acc[i][j] + b0[o0 + j];
        h0[(size_t)gr * Hd + o0 + j] = fmaxf(v, 0.f);
      }
    }
  }
}

// ---------- fused GCNII layer ----------
// wave-per-node; W column in 64 VGPRs; support@W via unrolled readlane broadcast.

__global__ __launch_bounds__(256) void layer_kernel(
    const float* __restrict__ h_in, const float* __restrict__ h0v,
    float* __restrict__ h_out, const int* __restrict__ row_ptr,
    const int2* __restrict__ epack, const float* __restrict__ dinv,
    const float* __restrict__ W, float beta, float one_m_beta, int n) {
  int lane = threadIdx.x & 63;
  int wid  = threadIdx.x >> 6;
  float wreg[64];
  #pragma unroll
  for (int k = 0; k < 64; ++k) wreg[k] = W[k * 64 + lane];

  for (int i = blockIdx.x * 4 + wid; i < n; i += gridDim.x * 4) {
    float di = dinv[i];
    size_t rowb = (size_t)i * Hd;
    float acc = di * di * h_in[rowb + lane];          // self loop
    int e0 = row_ptr[i], e1 = row_ptr[i + 1];
    for (int e = e0; e < e1; ++e) {
      int2 ep = epack[e];
      acc += __int_as_float(ep.y) * h_in[(size_t)ep.x * Hd + lane];
    }
    float sup = 0.9f * acc + 0.1f * h0v[rowb + lane];
    float o0 = 0.f, o1 = 0.f, o2 = 0.f, o3 = 0.f;
    #pragma unroll
    for (int k = 0; k < 64; k += 4) {
      o0 += bcast(sup, k    ) * wreg[k    ];
      o1 += bcast(sup, k + 1) * wreg[k + 1];
      o2 += bcast(sup, k + 2) * wreg[k + 2];
      o3 += bcast(sup, k + 3) * wreg[k + 3];
    }
    float out = beta * ((o0 + o1) + (o2 + o3)) + one_m_beta * sup;
    h_out[rowb + lane] = fmaxf(out, 0.f);
  }
}

// ---------- head: log_softmax(h @ wf + bf) ----------

__global__ __launch_bounds__(256) void final_kernel(const float* __restrict__ h,
                                                    const float* __restrict__ wf,
                                                    const float* __restrict__ bfv,
                                                    float* __restrict__ out, int n) {
  int lane = threadIdx.x & 63;
  int wid  = threadIdx.x >> 6;
  int c = (lane < Cd) ? lane : 0;
  for (int i = blockIdx.x * 4 + wid; i < n; i += gridDim.x * 4) {
    float hv = h[(size_t)i * Hd + lane];
    float acc = 0.f;
    #pragma unroll
    for (int k = 0; k < 64; ++k) acc += bcast(hv, k) * wf[k * Cd + c];
    float logit = acc + bfv[c];
    float m = (lane < Cd) ? logit : -1e30f;
    #pragma unroll
    for (int off = 32; off; off >>= 1) m = fmaxf(m, __shfl_xor(m, off, 64));
    float p = (lane < Cd) ? __expf(logit - m) : 0.f;
    #pragma unroll
    for (int off = 32; off; off >>= 1) p += __shfl_xor(p, off, 64);
    float lse = m + logf(p);
    if (lane < Cd) out[(size_t)i * Cd + lane] = logit - lse;
  }
}

// ---------- launch ----------

extern "C" void kernel_launch(void* const* d_in, const int* in_sizes, int n_in,
                              void* d_out, int out_size, void* d_ws, size_t ws_size,
                              hipStream_t stream) {
  const float* x  = (const float*)d_in[0];
  const int*   ei = (const int*)d_in[1];
  const float* w0 = (const float*)d_in[2];
  const float* b0 = (const float*)d_in[3];
  const float* wl = (const float*)d_in[4];
  const float* wf = (const float*)d_in[5];
  const float* bf = (const float*)d_in[6];
  int N = in_sizes[0] / Fd;
  int E = in_sizes[1] / 2;
  int L = in_sizes[4] / (Hd * Hd);
  float* out = (float*)d_out;

  char* w = (char*)d_ws;
  auto alloc = [&](size_t bytes) { char* p = w; w += (bytes + 255) & ~255ULL; return p; };
  int*   outdeg  = (int*)alloc((size_t)N * 4);
  int*   indeg   = (int*)alloc((size_t)N * 4);
  int*   row_ptr = (int*)alloc((size_t)(N + 1) * 4);
  int*   cursor  = (int*)alloc((size_t)N * 4);
  float* dinv    = (float*)alloc((size_t)N * 4);
  int2*  epack   = (int2*)alloc((size_t)E * 8);
  float* h0      = (float*)alloc((size_t)N * Hd * 4);
  float* hA      = (float*)alloc((size_t)N * Hd * 4);
  float* hB      = (float*)alloc((size_t)N * Hd * 4);

  hipMemsetAsync(outdeg, 0, (size_t)N * 4, stream);
  hipMemsetAsync(indeg,  0, (size_t)N * 4, stream);

  int tb = 256;
  count_kernel<<<(E + tb - 1) / tb, tb, 0, stream>>>(ei, E, outdeg, indeg);
  dinv_kernel<<<(N + tb - 1) / tb, tb, 0, stream>>>(outdeg, dinv, N);
  scan_kernel<<<1, 1024, 0, stream>>>(indeg, row_ptr, cursor, N);
  scatter_kernel<<<(E + tb - 1) / tb, tb, 0, stream>>>(ei, E, dinv, cursor, epack);

  gin_kernel<<<(N + GIN_BN - 1) / GIN_BN, 128, 0, stream>>>(x, w0, b0, h0, N);

  const float* cur = h0;
  float* bufs[2] = {hA, hB};
  for (int l = 0; l < L; ++l) {
    double beta = log(0.5 / (double)(l + 1) + 1.0);
    float* nxt = bufs[l & 1];
    layer_kernel<<<1024, 256, 0, stream>>>(cur, h0, nxt, row_ptr, epack, dinv,
                                           wl + (size_t)l * Hd * Hd,
                                           (float)beta, (float)(1.0 - beta), N);
    cur = nxt;
  }
  final_kernel<<<1024, 256, 0, stream>>>(cur, wf, bf, out, N);
}

// Round 2
// 2551.123 us; speedup vs baseline: 1.9615x; 1.9615x over previous
//
#include <hip/hip_runtime.h>
#include <hip/hip_bf16.h>
#include <math.h>

#define Hd 64
#define Fd 512
#define Cd 40
#define PCHUNK 512

typedef unsigned int uint;
typedef unsigned short ushort;

__device__ __forceinline__ float bcast(float v, int lane) {
  return __int_as_float(__builtin_amdgcn_readlane(__float_as_int(v), lane));
}
__device__ __forceinline__ ushort f2bf(float f) {
  union { float f; uint u; } c; c.f = f;
  uint r = c.u + 0x7fffu + ((c.u >> 16) & 1u);   // round-to-nearest-even
  return (ushort)(r >> 16);
}
__device__ __forceinline__ float bf2f(ushort s) {
  union { uint u; float f; } c; c.u = ((uint)s) << 16; return c.f;
}
__device__ __forceinline__ float bflo(uint u) { return __uint_as_float(u << 16); }
__device__ __forceinline__ float bfhi(uint u) { return __uint_as_float(u & 0xffff0000u); }

// ---------------- preprocessing ----------------

__global__ void count_kernel(const int* __restrict__ ei, int E,
                             int* __restrict__ outdeg, int* __restrict__ indeg) {
  int e = blockIdx.x * blockDim.x + threadIdx.x;
  if (e < E) {
    atomicAdd(&outdeg[ei[e]], 1);      // reference: deg over src (+ self loop)
    atomicAdd(&indeg[ei[E + e]], 1);   // CSR by dst
  }
}

__global__ void dinv_kernel(const int* __restrict__ outdeg, float* __restrict__ dinv, int n) {
  int i = blockIdx.x * blockDim.x + threadIdx.x;
  if (i < n) dinv[i] = rsqrtf((float)(outdeg[i] + 1));
}

__global__ __launch_bounds__(256) void pp_bsum(const int* __restrict__ counts, int n,
                                               int* __restrict__ bsum) {
  __shared__ int lds[256];
  int b = blockIdx.x, t = threadIdx.x;
  int i0 = b * PCHUNK + t;
  int s = 0;
  if (i0 < n) s += counts[i0];
  if (i0 + 256 < n) s += counts[i0 + 256];
  lds[t] = s; __syncthreads();
  for (int off = 128; off; off >>= 1) { if (t < off) lds[t] += lds[t + off]; __syncthreads(); }
  if (t == 0) bsum[b] = lds[0];
}

__global__ __launch_bounds__(256) void pp_bscan(const int* __restrict__ bsum, int nb,
                                                int* __restrict__ boff,
                                                int* __restrict__ row_ptr, int n) {
  __shared__ int lds[256];
  int t = threadIdx.x;
  int v = (t < nb) ? bsum[t] : 0;
  lds[t] = v; __syncthreads();
  for (int off = 1; off < 256; off <<= 1) {
    int x = (t >= off) ? lds[t - off] : 0;
    __syncthreads(); lds[t] += x; __syncthreads();
  }
  if (t < nb) boff[t] = lds[t] - v;   // exclusive
  if (t == 0) row_ptr[n] = lds[255];  // total = E
}

__global__ __launch_bounds__(256) void pp_scan(const int* __restrict__ counts, int n,
                                               const int* __restrict__ boff,
                                               int* __restrict__ row_ptr,
                                               int* __restrict__ cursor) {
  __shared__ int lds[256];
  int b = blockIdx.x, t = threadIdx.x;
  int i0 = b * PCHUNK + 2 * t;
  int c0 = (i0 < n) ? counts[i0] : 0;
  int c1 = (i0 + 1 < n) ? counts[i0 + 1] : 0;
  int ps = c0 + c1;
  lds[t] = ps; __syncthreads();
  for (int off = 1; off < 256; off <<= 1) {
    int x = (t >= off) ? lds[t - off] : 0;
    __syncthreads(); lds[t] += x; __syncthreads();
  }
  int excl = lds[t] - ps + boff[b];
  if (i0 < n)     { row_ptr[i0] = excl;          cursor[i0] = excl; }
  if (i0 + 1 < n) { row_ptr[i0 + 1] = excl + c0; cursor[i0 + 1] = excl + c0; }
}

__global__ void scatter_kernel(const int* __restrict__ ei, int E,
                               int* __restrict__ cursor, int* __restrict__ esrc) {
  int e = blockIdx.x * blockDim.x + threadIdx.x;
  if (e < E) {
    int s = ei[e], d = ei[E + e];
    int pos = atomicAdd(&cursor[d], 1);
    esrc[pos] = s;
  }
}

// ---------------- input projection: h0 = relu(x @ w0 + b0) ----------------

#define GIN_BN 64
#define GIN_TK 64

__global__ __launch_bounds__(128) void gin_kernel(const float* __restrict__ x,
                                                  const float* __restrict__ w0,
                                                  const float* __restrict__ b0,
                                                  const float* __restrict__ dinv,
                                                  ushort* __restrict__ h0b,
                                                  ushort* __restrict__ g0,
                                                  int n) {
  __shared__ float xs[GIN_BN][GIN_TK + 4];
  __shared__ float ws[GIN_TK][Hd];
  int tid = threadIdx.x;
  int o_grp = tid & 7;
  int n_grp = tid >> 3;
  int o0 = o_grp * 8;
  int base = blockIdx.x * GIN_BN;
  float acc[4][8];
  #pragma unroll
  for (int i = 0; i < 4; ++i)
    #pragma unroll
    for (int j = 0; j < 8; ++j) acc[i][j] = 0.f;

  for (int k0 = 0; k0 < Fd; k0 += GIN_TK) {
    int r  = tid >> 1;
    int c0 = (tid & 1) * 32;
    int gr = base + r;
    const float* src  = x + (size_t)gr * Fd + k0 + c0;
    const float* wsrc = w0 + (size_t)(k0 + r) * Hd + c0;
    #pragma unroll
    for (int q = 0; q < 8; ++q) {
      float4 v = (gr < n) ? *(const float4*)(src + q * 4) : make_float4(0.f, 0.f, 0.f, 0.f);
      *(float4*)&xs[r][c0 + q * 4] = v;
      *(float4*)&ws[r][c0 + q * 4] = *(const float4*)(wsrc + q * 4);
    }
    __syncthreads();
    #pragma unroll 4
    for (int k = 0; k < GIN_TK; ++k) {
      float xv[4];
      #pragma unroll
      for (int i = 0; i < 4; ++i) xv[i] = xs[n_grp * 4 + i][k];
      float wv[8];
      *(float4*)&wv[0] = *(float4*)&ws[k][o0];
      *(float4*)&wv[4] = *(float4*)&ws[k][o0 + 4];
      #pragma unroll
      for (int i = 0; i < 4; ++i)
        #pragma unroll
        for (int j = 0; j < 8; ++j) acc[i][j] += xv[i] * wv[j];
    }
    __syncthreads();
  }
  #pragma unroll
  for (int i = 0; i < 4; ++i) {
    int gr = base + n_grp * 4 + i;
    if (gr < n) {
      float dv = dinv[gr];
      #pragma unroll
      for (int j = 0; j < 8; j += 2) {
        float v0 = fmaxf(acc[i][j]     + b0[o0 + j],     0.f);
        float v1 = fmaxf(acc[i][j + 1] + b0[o0 + j + 1], 0.f);
        uint hp = (uint)f2bf(v0) | ((uint)f2bf(v1) << 16);
        uint gp = (uint)f2bf(v0 * dv) | ((uint)f2bf(v1 * dv) << 16);
        *(uint*)&h0b[(size_t)gr * Hd + o0 + j] = hp;
        *(uint*)&g0 [(size_t)gr * Hd + o0 + j] = gp;
      }
    }
  }
}

// ---------------- aggregation: agg[i] = dinv[i] * (sum_{src->i} g[src] + g[i]) ----------------
// 2 nodes per wave (half-wave each); lane holds 2 bf16 features (one uint);
// edge loop unrolled x4 with predication for MLP.

__global__ __launch_bounds__(256) void agg_kernel(const ushort* __restrict__ g,
                                                  const int* __restrict__ row_ptr,
                                                  const int* __restrict__ esrc,
                                                  const float* __restrict__ dinv,
                                                  float* __restrict__ aggout, int n) {
  int lane = threadIdx.x & 63;
  int half = lane >> 5;
  int l2 = lane & 31;
  int gw = (int)((blockIdx.x * blockDim.x + threadIdx.x) >> 6);
  int nw = (int)((gridDim.x * blockDim.x) >> 6);
  int npairs = (n + 1) >> 1;
  const uint* gu = (const uint*)g;

  for (int p = gw; p < npairs; p += nw) {
    int node = 2 * p + half;
    bool valid = node < n;
    int nn = valid ? node : 0;
    int e    = row_ptr[nn];
    int eend = valid ? row_ptr[nn + 1] : 0;
    uint us = gu[(size_t)nn * 32 + l2];           // self row
    float a0 = bflo(us), a1 = bfhi(us);
    float b0 = 0.f, b1 = 0.f, c0 = 0.f, c1 = 0.f, d0 = 0.f, d1 = 0.f;
    while (__any(e < eend)) {
      bool v0 = e     < eend;
      bool v1 = e + 1 < eend;
      bool v2 = e + 2 < eend;
      bool v3 = e + 3 < eend;
      int s0 = v0 ? esrc[e]     : 0;
      int s1 = v1 ? esrc[e + 1] : 0;
      int s2 = v2 ? esrc[e + 2] : 0;
      int s3 = v3 ? esrc[e + 3] : 0;
      uint u0 = gu[(size_t)s0 * 32 + l2];
      uint u1 = gu[(size_t)s1 * 32 + l2];
      uint u2 = gu[(size_t)s2 * 32 + l2];
      uint u3 = gu[(size_t)s3 * 32 + l2];
      if (!v0) u0 = 0; if (!v1) u1 = 0; if (!v2) u2 = 0; if (!v3) u3 = 0;
      a0 += bflo(u0); a1 += bfhi(u0);
      b0 += bflo(u1); b1 += bfhi(u1);
      c0 += bflo(u2); c1 += bfhi(u2);
      d0 += bflo(u3); d1 += bfhi(u3);
      e += 4;
    }
    float di = dinv[nn];
    float r0 = di * ((a0 + b0) + (c0 + d0));
    float r1 = di * ((a1 + b1) + (c1 + d1));
    if (valid) {
      float2* dst = (float2*)(aggout + (size_t)node * Hd);
      dst[l2] = make_float2(r0, r1);
    }
  }
}

// ---------------- layer matmul: g_out = bf16(relu(sup @ W') * dinv), W' = beta*W + (1-beta)*I ----------------

__global__ __launch_bounds__(256) void mat_kernel(const float* __restrict__ agg,
                                                  const ushort* __restrict__ h0b,
                                                  const float* __restrict__ dinv,
                                                  const float* __restrict__ W,
                                                  ushort* __restrict__ gout,
                                                  float beta, int n) {
  int lane = threadIdx.x & 63;
  float omb = 1.f - beta;
  float wreg[64];
  #pragma unroll
  for (int k = 0; k < 64; ++k) {
    float w = beta * W[k * 64 + lane];
    if (k == lane) w += omb;          // fold (1-beta)*I
    wreg[k] = w;
    asm volatile("" : "+v"(wreg[k]));  // pin in VGPR (stop rematerialized reloads)
  }
  int gw = (int)((blockIdx.x * blockDim.x + threadIdx.x) >> 6);
  int nw = (int)((gridDim.x * blockDim.x) >> 6);
  for (int i = gw; i < n; i += nw) {
    size_t rb = (size_t)i * Hd;
    float sup = 0.9f * agg[rb + lane] + 0.1f * bf2f(h0b[rb + lane]);
    float o0 = 0.f, o1 = 0.f, o2 = 0.f, o3 = 0.f;
    #pragma unroll
    for (int k = 0; k < 64; k += 4) {
      o0 += bcast(sup, k    ) * wreg[k    ];
      o1 += bcast(sup, k + 1) * wreg[k + 1];
      o2 += bcast(sup, k + 2) * wreg[k + 2];
      o3 += bcast(sup, k + 3) * wreg[k + 3];
    }
    float res = fmaxf((o0 + o1) + (o2 + o3), 0.f);
    gout[rb + lane] = f2bf(res * dinv[i]);
  }
}

// ---------------- head: log_softmax((g/dinv) @ wf + bf) ----------------

__global__ __launch_bounds__(256) void final_kernel(const ushort* __restrict__ g,
                                                    const int* __restrict__ outdeg,
                                                    const float* __restrict__ wf,
                                                    const float* __restrict__ bfv,
                                                    float* __restrict__ out, int n) {
  int lane = threadIdx.x & 63;
  int c = (lane < Cd) ? lane : 0;
  int gw = (int)((blockIdx.x * blockDim.x + threadIdx.x) >> 6);
  int nw = (int)((gridDim.x * blockDim.x) >> 6);
  for (int i = gw; i < n; i += nw) {
    float rdi = sqrtf((float)(outdeg[i] + 1));    // 1/dinv
    float hv = bf2f(g[(size_t)i * Hd + lane]) * rdi;
    float acc = 0.f;
    #pragma unroll
    for (int k = 0; k < 64; ++k) acc += bcast(hv, k) * wf[k * Cd + c];
    float logit = acc + bfv[c];
    float m = (lane < Cd) ? logit : -1e30f;
    #pragma unroll
    for (int off = 32; off; off >>= 1) m = fmaxf(m, __shfl_xor(m, off, 64));
    float p = (lane < Cd) ? __expf(logit - m) : 0.f;
    #pragma unroll
    for (int off = 32; off; off >>= 1) p += __shfl_xor(p, off, 64);
    float lse = m + logf(p);
    if (lane < Cd) out[(size_t)i * Cd + lane] = logit - lse;
  }
}

// ---------------- launch ----------------

extern "C" void kernel_launch(void* const* d_in, const int* in_sizes, int n_in,
                              void* d_out, int out_size, void* d_ws, size_t ws_size,
                              hipStream_t stream) {
  const float* x  = (const float*)d_in[0];
  const int*   ei = (const int*)d_in[1];
  const float* w0 = (const float*)d_in[2];
  const float* b0 = (const float*)d_in[3];
  const float* wl = (const float*)d_in[4];
  const float* wf = (const float*)d_in[5];
  const float* bf = (const float*)d_in[6];
  int N = in_sizes[0] / Fd;
  int E = in_sizes[1] / 2;
  int L = in_sizes[4] / (Hd * Hd);
  float* out = (float*)d_out;

  char* w = (char*)d_ws;
  auto alloc = [&](size_t bytes) { char* p = w; w += (bytes + 255) & ~255ULL; return p; };
  int*    outdeg  = (int*)alloc((size_t)N * 4);
  int*    indeg   = (int*)alloc((size_t)N * 4);
  int*    row_ptr = (int*)alloc((size_t)(N + 1) * 4);
  int*    cursor  = (int*)alloc((size_t)N * 4);
  float*  dinv    = (float*)alloc((size_t)N * 4);
  int*    bsum    = (int*)alloc(1024);
  int*    boff    = (int*)alloc(1024);
  int*    esrc    = (int*)alloc((size_t)E * 4);
  ushort* h0b     = (ushort*)alloc((size_t)N * Hd * 2);
  ushort* gA      = (ushort*)alloc((size_t)N * Hd * 2);
  ushort* gB      = (ushort*)alloc((size_t)N * Hd * 2);
  float*  aggb    = (float*)alloc((size_t)N * Hd * 4);

  hipMemsetAsync(outdeg, 0, (size_t)N * 4, stream);
  hipMemsetAsync(indeg,  0, (size_t)N * 4, stream);

  int tb = 256;
  int nb = (N + PCHUNK - 1) / PCHUNK;   // 196 for N=100000 (must be <= 256)
  count_kernel<<<(E + tb - 1) / tb, tb, 0, stream>>>(ei, E, outdeg, indeg);
  dinv_kernel<<<(N + tb - 1) / tb, tb, 0, stream>>>(outdeg, dinv, N);
  pp_bsum<<<nb, 256, 0, stream>>>(indeg, N, bsum);
  pp_bscan<<<1, 256, 0, stream>>>(bsum, nb, boff, row_ptr, N);
  pp_scan<<<nb, 256, 0, stream>>>(indeg, N, boff, row_ptr, cursor);
  scatter_kernel<<<(E + tb - 1) / tb, tb, 0, stream>>>(ei, E, cursor, esrc);

  gin_kernel<<<(N + GIN_BN - 1) / GIN_BN, 128, 0, stream>>>(x, w0, b0, dinv, h0b, gA, N);

  ushort* cur = gA;
  ushort* bufs[2] = {gB, gA};
  for (int l = 0; l < L; ++l) {
    double beta = log(0.5 / (double)(l + 1) + 1.0);
    ushort* nxt = bufs[l & 1];
    agg_kernel<<<2048, 256, 0, stream>>>(cur, row_ptr, esrc, dinv, aggb, N);
    mat_kernel<<<2048, 256, 0, stream>>>(aggb, h0b, dinv, wl + (size_t)l * Hd * Hd,
                                         nxt, (float)beta, N);
    cur = nxt;
  }
  final_kernel<<<2048, 256, 0, stream>>>(cur, outdeg, wf, bf, out, N);
}

// Round 3
// 1916.203 us; speedup vs baseline: 2.6114x; 1.3313x over previous
//
#include <hip/hip_runtime.h>
#include <hip/hip_bf16.h>
#include <math.h>

#define Hd 64
#define Fd 512
#define Cd 40
#define PCHUNK 512

typedef unsigned int uint;
typedef unsigned short ushort;

using bfrag  = __attribute__((ext_vector_type(8))) short;  // 8 bf16 = 4 VGPR
using floatx4 = __attribute__((ext_vector_type(4))) float; // MFMA C/D

__device__ __forceinline__ float bcast(float v, int lane) {
  return __int_as_float(__builtin_amdgcn_readlane(__float_as_int(v), lane));
}
__device__ __forceinline__ ushort f2bf(float f) {
  union { float f; uint u; } c; c.f = f;
  uint r = c.u + 0x7fffu + ((c.u >> 16) & 1u);   // RNE
  return (ushort)(r >> 16);
}
__device__ __forceinline__ float bf2f(ushort s) {
  union { uint u; float f; } c; c.u = ((uint)s) << 16; return c.f;
}
__device__ __forceinline__ float bflo(uint u) { return __uint_as_float(u << 16); }
__device__ __forceinline__ float bfhi(uint u) { return __uint_as_float(u & 0xffff0000u); }

// ---------------- preprocessing ----------------

__global__ void count_kernel(const int* __restrict__ ei, int E,
                             int* __restrict__ outdeg, int* __restrict__ indeg) {
  int e = blockIdx.x * blockDim.x + threadIdx.x;
  if (e < E) {
    atomicAdd(&outdeg[ei[e]], 1);      // deg over src (reference semantics)
    atomicAdd(&indeg[ei[E + e]], 1);   // CSR by dst
  }
}

__global__ void dinv_kernel(const int* __restrict__ outdeg, float* __restrict__ dinv, int n) {
  int i = blockIdx.x * blockDim.x + threadIdx.x;
  if (i < n) dinv[i] = rsqrtf((float)(outdeg[i] + 1));
}

__global__ __launch_bounds__(256) void pp_bsum(const int* __restrict__ counts, int n,
                                               int* __restrict__ bsum) {
  __shared__ int lds[256];
  int b = blockIdx.x, t = threadIdx.x;
  int i0 = b * PCHUNK + t;
  int s = 0;
  if (i0 < n) s += counts[i0];
  if (i0 + 256 < n) s += counts[i0 + 256];
  lds[t] = s; __syncthreads();
  for (int off = 128; off; off >>= 1) { if (t < off) lds[t] += lds[t + off]; __syncthreads(); }
  if (t == 0) bsum[b] = lds[0];
}

__global__ __launch_bounds__(256) void pp_bscan(const int* __restrict__ bsum, int nb,
                                                int* __restrict__ boff,
                                                int* __restrict__ row_ptr, int n) {
  __shared__ int lds[256];
  int t = threadIdx.x;
  int v = (t < nb) ? bsum[t] : 0;
  lds[t] = v; __syncthreads();
  for (int off = 1; off < 256; off <<= 1) {
    int x = (t >= off) ? lds[t - off] : 0;
    __syncthreads(); lds[t] += x; __syncthreads();
  }
  if (t < nb) boff[t] = lds[t] - v;
  if (t == 0) row_ptr[n] = lds[255];
}

__global__ __launch_bounds__(256) void pp_scan(const int* __restrict__ counts, int n,
                                               const int* __restrict__ boff,
                                               int* __restrict__ row_ptr,
                                               int* __restrict__ cursor) {
  __shared__ int lds[256];
  int b = blockIdx.x, t = threadIdx.x;
  int i0 = b * PCHUNK + 2 * t;
  int c0 = (i0 < n) ? counts[i0] : 0;
  int c1 = (i0 + 1 < n) ? counts[i0 + 1] : 0;
  int ps = c0 + c1;
  lds[t] = ps; __syncthreads();
  for (int off = 1; off < 256; off <<= 1) {
    int x = (t >= off) ? lds[t - off] : 0;
    __syncthreads(); lds[t] += x; __syncthreads();
  }
  int excl = lds[t] - ps + boff[b];
  if (i0 < n)     { row_ptr[i0] = excl;          cursor[i0] = excl; }
  if (i0 + 1 < n) { row_ptr[i0 + 1] = excl + c0; cursor[i0 + 1] = excl + c0; }
}

__global__ void scatter_kernel(const int* __restrict__ ei, int E,
                               int* __restrict__ cursor, int* __restrict__ esrc) {
  int e = blockIdx.x * blockDim.x + threadIdx.x;
  if (e < E) {
    int s = ei[e], d = ei[E + e];
    int pos = atomicAdd(&cursor[d], 1);
    esrc[pos] = s;
  }
}

// ---------------- weight prep ----------------
// w0T[o][k] = bf16(w0[k][o])                 (64 x 512)
__global__ void w0prep(const float* __restrict__ w0, ushort* __restrict__ w0T) {
  int i = blockIdx.x * 256 + threadIdx.x;
  if (i < Hd * Fd) {
    int o = i >> 9, k = i & 511;
    w0T[i] = f2bf(w0[(size_t)k * Hd + o]);
  }
}
// WT[l][o][k] = bf16(beta_l * wl[l][k][o] + (k==o ? 1-beta_l : 0))
__global__ void wprep(const float* __restrict__ wl, ushort* __restrict__ WT, int L) {
  int i = blockIdx.x * 256 + threadIdx.x;
  if (i < L * Hd * Hd) {
    int l = i >> 12, rem = i & 4095, o = rem >> 6, k = rem & 63;
    float beta = logf(0.5f / (float)(l + 1) + 1.f);
    float w = beta * wl[(size_t)l * 4096 + k * 64 + o];
    if (k == o) w += 1.f - beta;
    WT[i] = f2bf(w);
  }
}

// ---------------- input projection (MFMA, LDS-free) ----------------
// block = 256 (4 waves), 32 nodes/wave -> 128 nodes/block; K = 512 in steps of 32.
// A: per-lane f32 loads from x -> bf16. B: w0T bf16 (16B/lane, L2-hot).
// Writes h0q and g (layer-0), both as 4 feature-quarter slabs [q][N][16] bf16.

__global__ __launch_bounds__(256) void gin_kernel(const float* __restrict__ x,
                                                  const ushort* __restrict__ w0T,
                                                  const float* __restrict__ b0,
                                                  const float* __restrict__ dinv,
                                                  ushort* __restrict__ h0q,
                                                  ushort* __restrict__ gq,
                                                  int n) {
  int wave = threadIdx.x >> 6;
  int lane = threadIdx.x & 63;
  int lrow = lane & 15;
  int lk   = lane >> 4;          // k-group 0..3
  int nb   = blockIdx.x * 128 + wave * 32;

  floatx4 acc[2][4];
  #pragma unroll
  for (int m = 0; m < 2; ++m)
    #pragma unroll
    for (int o = 0; o < 4; ++o) acc[m][o] = floatx4{0.f, 0.f, 0.f, 0.f};

  for (int k0 = 0; k0 < Fd; k0 += 32) {
    bfrag a[2], b[4];
    #pragma unroll
    for (int m = 0; m < 2; ++m) {
      int node = nb + m * 16 + lrow; if (node >= n) node = n - 1;
      const float* px = x + (size_t)node * Fd + k0 + lk * 8;
      float4 lo = *(const float4*)px;
      float4 hi = *(const float4*)(px + 4);
      a[m][0] = (short)f2bf(lo.x); a[m][1] = (short)f2bf(lo.y);
      a[m][2] = (short)f2bf(lo.z); a[m][3] = (short)f2bf(lo.w);
      a[m][4] = (short)f2bf(hi.x); a[m][5] = (short)f2bf(hi.y);
      a[m][6] = (short)f2bf(hi.z); a[m][7] = (short)f2bf(hi.w);
    }
    #pragma unroll
    for (int o = 0; o < 4; ++o)
      b[o] = *(const bfrag*)(w0T + (size_t)(o * 16 + lrow) * Fd + k0 + lk * 8);
    #pragma unroll
    for (int m = 0; m < 2; ++m)
      #pragma unroll
      for (int o = 0; o < 4; ++o)
        acc[m][o] = __builtin_amdgcn_mfma_f32_16x16x32_bf16(a[m], b[o], acc[m][o], 0, 0, 0);
  }

  float b0v[4];
  #pragma unroll
  for (int o = 0; o < 4; ++o) b0v[o] = b0[o * 16 + lrow];

  #pragma unroll
  for (int m = 0; m < 2; ++m) {
    #pragma unroll
    for (int r = 0; r < 4; ++r) {
      int node = nb + m * 16 + lk * 4 + r;   // C/D: row=(lane>>4)*4+reg, col=lane&15
      bool ok = node < n;
      int nn = ok ? node : 0;
      float dv = dinv[nn];
      #pragma unroll
      for (int o = 0; o < 4; ++o) {
        float v = fmaxf(acc[m][o][r] + b0v[o], 0.f);
        if (ok) {
          size_t idx = ((size_t)o * n + nn) * 16 + lrow;
          h0q[idx] = f2bf(v);
          gq[idx]  = f2bf(v * dv);
        }
      }
    }
  }
}

// ---------------- aggregation + support (quartered, XCD-pinned) ----------------
// quarter = (blockIdx%8)>>1 : each XCD pair gathers only its 3.2 MB slab.
// wave = 8 node-groups x 8 lanes; lane holds 2 bf16 features (uint).
// sup = bf16(0.9*dinv[i]*(sum g[src] + g[i]) + 0.1*h0[i])

__global__ __launch_bounds__(256) void agg_kernel(const ushort* __restrict__ gq,
                                                  const ushort* __restrict__ h0q,
                                                  const int* __restrict__ row_ptr,
                                                  const int* __restrict__ esrc,
                                                  const float* __restrict__ dinv,
                                                  ushort* __restrict__ supq,
                                                  int n) {
  int lane = threadIdx.x & 63;
  int rl   = lane & 7;         // uint index within 32B quarter-row
  int grp  = lane >> 3;        // node group 0..7
  int q       = (blockIdx.x & 7) >> 1;
  int blkInQ  = ((blockIdx.x >> 3) << 1) | (blockIdx.x & 1);
  int wv  = blkInQ * 4 + (threadIdx.x >> 6);
  int nwv = (gridDim.x >> 2) * 4;

  const uint* gu = (const uint*)gq  + (size_t)q * n * 8;
  const uint* hu = (const uint*)h0q + (size_t)q * n * 8;
  uint*       su = (uint*)supq      + (size_t)q * n * 8;

  int ngroups = (n + 7) >> 3;
  for (int g = wv; g < ngroups; g += nwv) {
    int node = g * 8 + grp;
    bool ok = node < n;
    int nn = ok ? node : 0;
    int e    = row_ptr[nn];
    int eend = ok ? row_ptr[nn + 1] : e;
    uint us = gu[(size_t)nn * 8 + rl];
    float a0 = bflo(us), a1 = bfhi(us);
    float b0 = 0.f, b1 = 0.f, c0 = 0.f, c1 = 0.f, d0 = 0.f, d1 = 0.f;
    while (__any(e < eend)) {
      bool v0 = e < eend, v1 = e + 1 < eend, v2 = e + 2 < eend, v3 = e + 3 < eend;
      int s0 = v0 ? esrc[e]     : 0;
      int s1 = v1 ? esrc[e + 1] : 0;
      int s2 = v2 ? esrc[e + 2] : 0;
      int s3 = v3 ? esrc[e + 3] : 0;
      uint u0 = gu[(size_t)s0 * 8 + rl];
      uint u1 = gu[(size_t)s1 * 8 + rl];
      uint u2 = gu[(size_t)s2 * 8 + rl];
      uint u3 = gu[(size_t)s3 * 8 + rl];
      if (!v0) u0 = 0; if (!v1) u1 = 0; if (!v2) u2 = 0; if (!v3) u3 = 0;
      a0 += bflo(u0); a1 += bfhi(u0);
      b0 += bflo(u1); b1 += bfhi(u1);
      c0 += bflo(u2); c1 += bfhi(u2);
      d0 += bflo(u3); d1 += bfhi(u3);
      e += 4;
    }
    float di = dinv[nn];
    uint h = hu[(size_t)nn * 8 + rl];
    float s0v = 0.9f * di * ((a0 + b0) + (c0 + d0)) + 0.1f * bflo(h);
    float s1v = 0.9f * di * ((a1 + b1) + (c1 + d1)) + 0.1f * bfhi(h);
    if (ok) su[(size_t)nn * 8 + rl] = (uint)f2bf(s0v) | ((uint)f2bf(s1v) << 16);
  }
}

// ---------------- layer matmul (MFMA): g_out = bf16(relu(sup @ W') * dinv) ----------------

__global__ __launch_bounds__(256) void mat_kernel(const ushort* __restrict__ supq,
                                                  const float* __restrict__ dinv,
                                                  const ushort* __restrict__ WT,  // [64][64] bf16
                                                  ushort* __restrict__ goutq,
                                                  int n) {
  int wave = threadIdx.x >> 6;
  int lane = threadIdx.x & 63;
  int lrow = lane & 15;
  int lk   = lane >> 4;
  int nb   = blockIdx.x * 128 + wave * 32;

  bfrag b[4][2];
  #pragma unroll
  for (int o = 0; o < 4; ++o)
    #pragma unroll
    for (int s = 0; s < 2; ++s)
      b[o][s] = *(const bfrag*)(WT + (size_t)(o * 16 + lrow) * 64 + s * 32 + lk * 8);

  floatx4 acc[2][4];
  #pragma unroll
  for (int m = 0; m < 2; ++m)
    #pragma unroll
    for (int o = 0; o < 4; ++o) acc[m][o] = floatx4{0.f, 0.f, 0.f, 0.f};

  #pragma unroll
  for (int m = 0; m < 2; ++m) {
    int node = nb + m * 16 + lrow; if (node >= n) node = n - 1;
    bfrag a0, a1;
    { int k = lk * 8;      a0 = *(const bfrag*)(supq + ((size_t)(k >> 4) * n + node) * 16 + (k & 15)); }
    { int k = 32 + lk * 8; a1 = *(const bfrag*)(supq + ((size_t)(k >> 4) * n + node) * 16 + (k & 15)); }
    #pragma unroll
    for (int o = 0; o < 4; ++o) {
      acc[m][o] = __builtin_amdgcn_mfma_f32_16x16x32_bf16(a0, b[o][0], acc[m][o], 0, 0, 0);
      acc[m][o] = __builtin_amdgcn_mfma_f32_16x16x32_bf16(a1, b[o][1], acc[m][o], 0, 0, 0);
    }
  }

  #pragma unroll
  for (int m = 0; m < 2; ++m) {
    #pragma unroll
    for (int r = 0; r < 4; ++r) {
      int node = nb + m * 16 + lk * 4 + r;
      bool ok = node < n;
      int nn = ok ? node : 0;
      float dv = dinv[nn];
      #pragma unroll
      for (int o = 0; o < 4; ++o) {
        float v = fmaxf(acc[m][o][r], 0.f);
        if (ok) goutq[((size_t)o * n + nn) * 16 + lrow] = f2bf(v * dv);
      }
    }
  }
}

// ---------------- head: log_softmax((g/dinv) @ wf + bf) ----------------

__global__ __launch_bounds__(256) void final_kernel(const ushort* __restrict__ gq,
                                                    const int* __restrict__ outdeg,
                                                    const float* __restrict__ wf,
                                                    const float* __restrict__ bfv,
                                                    float* __restrict__ out, int n) {
  int lane = threadIdx.x & 63;
  int c = (lane < Cd) ? lane : 0;
  size_t qoff = (size_t)(lane >> 4) * n * 16 + (lane & 15);
  int gw = (int)((blockIdx.x * blockDim.x + threadIdx.x) >> 6);
  int nw = (int)((gridDim.x * blockDim.x) >> 6);
  for (int i = gw; i < n; i += nw) {
    float rdi = sqrtf((float)(outdeg[i] + 1));
    float hv = bf2f(gq[qoff + (size_t)i * 16]) * rdi;
    float acc = 0.f;
    #pragma unroll
    for (int k = 0; k < 64; ++k) acc += bcast(hv, k) * wf[k * Cd + c];
    float logit = acc + bfv[c];
    float m = (lane < Cd) ? logit : -1e30f;
    #pragma unroll
    for (int off = 32; off; off >>= 1) m = fmaxf(m, __shfl_xor(m, off, 64));
    float p = (lane < Cd) ? __expf(logit - m) : 0.f;
    #pragma unroll
    for (int off = 32; off; off >>= 1) p += __shfl_xor(p, off, 64);
    float lse = m + logf(p);
    if (lane < Cd) out[(size_t)i * Cd + lane] = logit - lse;
  }
}

// ---------------- launch ----------------

extern "C" void kernel_launch(void* const* d_in, const int* in_sizes, int n_in,
                              void* d_out, int out_size, void* d_ws, size_t ws_size,
                              hipStream_t stream) {
  const float* x  = (const float*)d_in[0];
  const int*   ei = (const int*)d_in[1];
  const float* w0 = (const float*)d_in[2];
  const float* b0 = (const float*)d_in[3];
  const float* wl = (const float*)d_in[4];
  const float* wf = (const float*)d_in[5];
  const float* bf = (const float*)d_in[6];
  int N = in_sizes[0] / Fd;
  int E = in_sizes[1] / 2;
  int L = in_sizes[4] / (Hd * Hd);
  float* out = (float*)d_out;

  char* w = (char*)d_ws;
  auto alloc = [&](size_t bytes) { char* p = w; w += (bytes + 255) & ~255ULL; return p; };
  int*    outdeg  = (int*)alloc((size_t)N * 4);
  int*    indeg   = (int*)alloc((size_t)N * 4);
  int*    row_ptr = (int*)alloc((size_t)(N + 1) * 4);
  int*    cursor  = (int*)alloc((size_t)N * 4);
  float*  dinv    = (float*)alloc((size_t)N * 4);
  int*    bsum    = (int*)alloc(1024);
  int*    boff    = (int*)alloc(1024);
  int*    esrc    = (int*)alloc((size_t)E * 4);
  ushort* w0T     = (ushort*)alloc((size_t)Hd * Fd * 2);
  ushort* WTall   = (ushort*)alloc((size_t)L * Hd * Hd * 2);
  ushort* h0q     = (ushort*)alloc((size_t)N * Hd * 2);
  ushort* gA      = (ushort*)alloc((size_t)N * Hd * 2);
  ushort* gB      = (ushort*)alloc((size_t)N * Hd * 2);
  ushort* supq    = (ushort*)alloc((size_t)N * Hd * 2);

  hipMemsetAsync(outdeg, 0, (size_t)N * 4, stream);
  hipMemsetAsync(indeg,  0, (size_t)N * 4, stream);

  int tb = 256;
  int nb = (N + PCHUNK - 1) / PCHUNK;
  count_kernel<<<(E + tb - 1) / tb, tb, 0, stream>>>(ei, E, outdeg, indeg);
  dinv_kernel<<<(N + tb - 1) / tb, tb, 0, stream>>>(outdeg, dinv, N);
  pp_bsum<<<nb, 256, 0, stream>>>(indeg, N, bsum);
  pp_bscan<<<1, 256, 0, stream>>>(bsum, nb, boff, row_ptr, N);
  pp_scan<<<nb, 256, 0, stream>>>(indeg, N, boff, row_ptr, cursor);
  scatter_kernel<<<(E + tb - 1) / tb, tb, 0, stream>>>(ei, E, cursor, esrc);

  w0prep<<<(Hd * Fd + 255) / 256, 256, 0, stream>>>(w0, w0T);
  wprep<<<(L * Hd * Hd + 255) / 256, 256, 0, stream>>>(wl, WTall, L);

  int gemm_grid = (N + 127) / 128;
  gin_kernel<<<gemm_grid, 256, 0, stream>>>(x, w0T, b0, dinv, h0q, gA, N);

  ushort* cur = gA;
  ushort* bufs[2] = {gB, gA};
  for (int l = 0; l < L; ++l) {
    ushort* nxt = bufs[l & 1];
    agg_kernel<<<2048, 256, 0, stream>>>(cur, h0q, row_ptr, esrc, dinv, supq, N);
    mat_kernel<<<gemm_grid, 256, 0, stream>>>(supq, dinv, WTall + (size_t)l * Hd * Hd, nxt, N);
    cur = nxt;
  }
  final_kernel<<<2048, 256, 0, stream>>>(cur, outdeg, wf, bf, out, N);
}